// Round 9
// baseline (195.215 us; speedup 1.0000x reference)
//
#include <hip/hip_runtime.h>
#include <math.h>

#define PI_F 3.14159265358979323846f

// Persistent device scratch (rewritten fully on every launch).
__device__ float g_rwT[576 * 64];  // res_proj_w transposed: [p][c]
__device__ float g_dwT[576 * 6];   // data_proj_w transposed: [p][q]
__device__ float g_Ur[64 * 64];    // fixed-circuit unitary, real part [t][s]
__device__ float g_Ui[64 * 64];    // imag part [t][s]
__device__ float g_Zw[64 * 64];    // Zw[t][c] = sum_q out_proj_w[c,q]*sign_q(t)
__device__ float g_sang[48];       // style angles [b][q] (tanh*pi applied)
__device__ float g_cb[64];         // out_proj_b + res_proj_b

// ---------------------------------------------------------------------------
// Prep, 64-thread blocks (unchanged from R5-R8 — proven fast).
//   bid 0      : Zw + combined bias
//   bid 1      : style angles
//   bid 2..65  : circuit column s = bid-2 (wave butterfly via __shfl_xor)
//   bid 66..641: weight transposes
__global__ __launch_bounds__(64) void k_prep(
        const float* __restrict__ style,
        const float* __restrict__ dw, const float* __restrict__ rw,
        const float* __restrict__ s2dw, const float* __restrict__ s2db,
        const float* __restrict__ qcnn, const float* __restrict__ meas,
        const float* __restrict__ outw, const float* __restrict__ outb,
        const float* __restrict__ resb) {
    int bid = blockIdx.x;
    int t = threadIdx.x;

    if (bid >= 66) {  // transposes
        int i = (bid - 66) * 64 + t;  // 0..36863
        if (i < 576 * 6) { int q = i / 576, p = i % 576; g_dwT[p * 6 + q] = dw[i]; }
        { int c = i / 576, p = i % 576; g_rwT[p * 64 + c] = rw[i]; }
        return;
    }
    if (bid == 0) {  // Zw row t + combined bias
        float zr[6];
#pragma unroll
        for (int q = 0; q < 6; ++q) zr[q] = ((t >> (5 - q)) & 1) ? -1.f : 1.f;
#pragma unroll 8
        for (int c = 0; c < 64; ++c) {
            float z = 0.f;
#pragma unroll
            for (int q = 0; q < 6; ++q) z += outw[c * 6 + q] * zr[q];
            g_Zw[t * 64 + c] = z;
        }
        g_cb[t] = outb[t] + resb[t];
        return;
    }
    if (bid == 1) {  // style angles [b][q]
        if (t < 48) {
            int bb = t / 6, q = t % 6;
            float a = s2db[q];
#pragma unroll 8
            for (int j = 0; j < 128; ++j) a += style[bb * 128 + j] * s2dw[q * 128 + j];
            g_sang[t] = tanhf(a) * PI_F;
        }
        return;
    }

    // Circuit column s: lane t holds amplitude of basis state t (wire q = bit 5-q).
    int s = bid - 2;
    float ar = (t == s) ? 1.f : 0.f;
    float ai = 0.f;

#pragma unroll
    for (int l = 0; l < 2; ++l) {
#pragma unroll
        for (int wq = 0; wq < 6; ++wq) {
            int mask = 1 << (5 - wq);
            bool hi = (t & mask) != 0;
            float th = qcnn[((l * 6 + wq) * 2 + 0) * 3];
            float sg, cg; sincosf(0.5f * th, &sg, &cg);
            float pr = __shfl_xor(ar, mask);
            float pi2 = __shfl_xor(ai, mask);
            ar = hi ? (sg * pr + cg * ar) : (cg * ar - sg * pr);
            ai = hi ? (sg * pi2 + cg * ai) : (cg * ai - sg * pi2);
            float ph = qcnn[((l * 6 + wq) * 2 + 1) * 3];
            float sz, cz; sincosf(0.5f * ph, &sz, &cz);
            float szz = hi ? sz : -sz;
            float nr = cz * ar - szz * ai;
            float ni = cz * ai + szz * ar;
            ar = nr; ai = ni;
        }
#pragma unroll
        for (int wq = 0; wq < 6; ++wq) {  // ring CNOTs
            int cm = 1 << (5 - wq);
            int tm = 1 << (5 - ((wq + 1) % 6));
            float pr = __shfl_xor(ar, tm);
            float pi2 = __shfl_xor(ai, tm);
            if (t & cm) { ar = pr; ai = pi2; }
        }
    }
#pragma unroll
    for (int wq = 0; wq < 6; ++wq) {  // U3 measurement basis
        int mask = 1 << (5 - wq);
        bool hi = (t & mask) != 0;
        float th = meas[wq * 3 + 0], ph = meas[wq * 3 + 1], lm = meas[wq * 3 + 2];
        float st2, ct; sincosf(0.5f * th, &st2, &ct);
        float sl, cl;  sincosf(lm, &sl, &cl);
        float sp, cp;  sincosf(ph, &sp, &cp);
        float spl, cpl; sincosf(ph + lm, &spl, &cpl);
        float u01r = -cl * st2, u01i = -sl * st2;
        float u10r =  cp * st2, u10i =  sp * st2;
        float u11r =  cpl * ct, u11i =  spl * ct;
        float pr = __shfl_xor(ar, mask);
        float pi2 = __shfl_xor(ai, mask);
        float nr, ni;
        if (hi) {
            nr = u10r * pr - u10i * pi2 + u11r * ar - u11i * ai;
            ni = u10r * pi2 + u10i * pr + u11r * ai + u11i * ar;
        } else {
            nr = ct * ar + u01r * pr - u01i * pi2;
            ni = ct * ai + u01r * pi2 + u01i * pr;
        }
        ar = nr; ai = ni;
    }
    g_Ur[t * 64 + s] = ar;
    g_Ui[t * 64 + s] = ai;
}

// ---------------------------------------------------------------------------
// Main (R8 structure + 3 cuts): 1024 threads = 64 pixels (lane) x 16 waves.
// wave wid: slice = wid&7 (output chans/states [8s,8s+8)), khalf = wid>>3
// (input chans [32k,32k+32)); both readfirstlane'd -> scalar weight loads.
// New vs R8: (1) angle pass fused into conv ((c>>2)==slice, wave-uniform);
// (2) lds_ang replaced by 6x66 atomicAdd buffer (LDS 74.7 -> 50.3 KB so two
// 16-wave blocks can co-reside); (3) conv c-loop unroll 8 (8 loads in flight).
__global__ __launch_bounds__(1024, 4) void k_main(const float* __restrict__ x,
                                                  const float* __restrict__ dpb,
                                                  float* __restrict__ out) {
    __shared__ float lds_angr[6 * 66];   // [q][pix] reduced angles   1.6 KB
    __shared__ float lds_acc[64 * 65];   // [pix][c] khalf1 partial  16.6 KB
    __shared__ float lds_psi[64 * 65];   // [pix][s]                 16.6 KB
    __shared__ float lds_prob[64 * 65];  // [pix][t]                 16.6 KB

    int tid  = threadIdx.x;
    int lane = tid & 63;                 // pixel within block (== w)
    int wid  = __builtin_amdgcn_readfirstlane(tid >> 6);  // 0..15
    int slice = wid & 7;
    int khalf = wid >> 3;
    int c0 = slice * 8;

    int p = blockIdx.x * 64 + lane;      // pixel id: b*4096 + h*64 + w
    int b = p >> 12;
    int h = (p >> 6) & 63;
    int w = p & 63;
    const float* xb = x + (b << 18);

    if (tid < 6 * 66) lds_angr[tid] = 0.f;

    // ---- fused conv + angle pass over this khalf's 32 input channels.
    // Angle channels of this wave are [4*slice, 4*slice+4) within the range.
    float acc[8];
#pragma unroll
    for (int k = 0; k < 8; ++k) acc[k] = 0.f;
    float ang[6] = {0.f, 0.f, 0.f, 0.f, 0.f, 0.f};
    int cb = khalf * 32;
#pragma unroll
    for (int i = 0; i < 3; ++i) {
        int hh = h + i - 1;
        bool hok = (unsigned)hh < 64u;
#pragma unroll
        for (int j = 0; j < 3; ++j) {
            int ww = w + j - 1;
            bool ok = hok && (unsigned)ww < 64u;
            const float* xij = xb + (hh << 6) + ww + (cb << 12);
            const float* wij = g_rwT + ((cb * 9) << 6) + ((i * 3 + j) << 6) + c0;
#pragma unroll 8
            for (int c = 0; c < 32; ++c) {
                float v = 0.f;
                if (ok) v = xij[c << 12];
                const float4 w0 = *(const float4*)(wij + c * 576);
                const float4 w1 = *(const float4*)(wij + c * 576 + 4);
                acc[0] += v * w0.x; acc[1] += v * w0.y;
                acc[2] += v * w0.z; acc[3] += v * w0.w;
                acc[4] += v * w1.x; acc[5] += v * w1.y;
                acc[6] += v * w1.z; acc[7] += v * w1.w;
                if ((c >> 2) == slice) {  // wave-uniform: this wave's angle chans
                    const float* dp = g_dwT + ((cb + c) * 9 + i * 3 + j) * 6;
#pragma unroll
                    for (int q = 0; q < 6; ++q) ang[q] += v * dp[q];
                }
            }
        }
    }
    __syncthreads();  // orders lds_angr init before the atomics below

    // ---- cross-wave angle reduction via LDS float atomics (ds_add_f32)
#pragma unroll
    for (int q = 0; q < 6; ++q) atomicAdd(&lds_angr[q * 66 + lane], ang[q]);
    // khalf=1 parks its conv partial (wave-uniform branch)
    if (khalf) {
#pragma unroll
        for (int k = 0; k < 8; ++k) lds_acc[lane * 65 + c0 + k] = acc[k];
    }
    __syncthreads();
    if (!khalf) {
#pragma unroll
        for (int k = 0; k < 8; ++k) acc[k] += lds_acc[lane * 65 + c0 + k];
    }

    // ---- finish theta, sincos
    float sc[6], cc[6];
#pragma unroll
    for (int q = 0; q < 6; ++q) {
        float t = lds_angr[q * 66 + lane];
        float theta = tanhf(t + dpb[q]) * PI_F + g_sang[b * 6 + q];
        sincosf(0.5f * theta, &sc[q], &cc[q]);
    }

    // ---- cooperative psi: this group builds states s = wid*4 .. wid*4+3
#pragma unroll
    for (int ti = 0; ti < 4; ++ti) {
        int s = wid * 4 + ti;
        float v = ((s >> 5) & 1) ? sc[0] : cc[0];
        v *= ((s >> 4) & 1) ? sc[1] : cc[1];
        v *= ((s >> 3) & 1) ? sc[2] : cc[2];
        v *= ((s >> 2) & 1) ? sc[3] : cc[3];
        v *= ((s >> 1) & 1) ? sc[4] : cc[4];
        v *= (s & 1)        ? sc[5] : cc[5];
        lds_psi[lane * 65 + s] = v;
    }
    __syncthreads();

    // ---- probs for this group's 4 states: stream psi from LDS in blocks of 8
    int t0 = wid * 4;
    float yr[4], yi[4];
#pragma unroll
    for (int t = 0; t < 4; ++t) { yr[t] = 0.f; yi[t] = 0.f; }
#pragma unroll
    for (int s0 = 0; s0 < 8; ++s0) {
        float ps[8];
#pragma unroll
        for (int k = 0; k < 8; ++k) ps[k] = lds_psi[lane * 65 + s0 * 8 + k];
#pragma unroll
        for (int t = 0; t < 4; ++t) {
            const float4 u0 = *(const float4*)(g_Ur + ((t0 + t) << 6) + s0 * 8);
            const float4 u1 = *(const float4*)(g_Ur + ((t0 + t) << 6) + s0 * 8 + 4);
            const float4 v0 = *(const float4*)(g_Ui + ((t0 + t) << 6) + s0 * 8);
            const float4 v1 = *(const float4*)(g_Ui + ((t0 + t) << 6) + s0 * 8 + 4);
            yr[t] += u0.x * ps[0] + u0.y * ps[1] + u0.z * ps[2] + u0.w * ps[3]
                   + u1.x * ps[4] + u1.y * ps[5] + u1.z * ps[6] + u1.w * ps[7];
            yi[t] += v0.x * ps[0] + v0.y * ps[1] + v0.z * ps[2] + v0.w * ps[3]
                   + v1.x * ps[4] + v1.y * ps[5] + v1.z * ps[6] + v1.w * ps[7];
        }
    }
#pragma unroll
    for (int t = 0; t < 4; ++t)
        lds_prob[lane * 65 + t0 + t] = yr[t] * yr[t] + yi[t] * yi[t];
    __syncthreads();

    // ---- khalf=0 folds probs through Zw into its 8 output channels + stores
    if (!khalf) {
#pragma unroll 8
        for (int t = 0; t < 64; ++t) {
            float pr = lds_prob[lane * 65 + t];
            const float4 z0 = *(const float4*)(g_Zw + (t << 6) + c0);
            const float4 z1 = *(const float4*)(g_Zw + (t << 6) + c0 + 4);
            acc[0] += pr * z0.x; acc[1] += pr * z0.y;
            acc[2] += pr * z0.z; acc[3] += pr * z0.w;
            acc[4] += pr * z1.x; acc[5] += pr * z1.y;
            acc[6] += pr * z1.z; acc[7] += pr * z1.w;
        }
        int ob = (b << 18) + (h << 6) + w;
#pragma unroll
        for (int k = 0; k < 8; ++k) {
            out[ob + ((c0 + k) << 12)] = acc[k] + g_cb[c0 + k];
        }
    }
}

// ---------------------------------------------------------------------------
extern "C" void kernel_launch(void* const* d_in, const int* in_sizes, int n_in,
                              void* d_out, int out_size, void* d_ws, size_t ws_size,
                              hipStream_t stream) {
    const float* x     = (const float*)d_in[0];
    const float* style = (const float*)d_in[1];
    const float* dw    = (const float*)d_in[2];
    const float* dpb   = (const float*)d_in[3];
    const float* s2dw  = (const float*)d_in[4];
    const float* s2db  = (const float*)d_in[5];
    const float* qcnn  = (const float*)d_in[6];
    const float* meas  = (const float*)d_in[7];
    const float* outw  = (const float*)d_in[8];
    const float* outb  = (const float*)d_in[9];
    const float* rw    = (const float*)d_in[10];
    const float* resb  = (const float*)d_in[11];
    float* out = (float*)d_out;

    hipLaunchKernelGGL(k_prep, dim3(642), dim3(64), 0, stream,
                       style, dw, rw, s2dw, s2db, qcnn, meas, outw, outb, resb);
    hipLaunchKernelGGL(k_main, dim3(512), dim3(1024), 0, stream, x, dpb, out);
}

// Round 10
// 162.419 us; speedup vs baseline: 1.2019x; 1.2019x over previous
//
#include <hip/hip_runtime.h>
#include <math.h>

#define PI_F 3.14159265358979323846f

// Persistent device scratch (rewritten fully on every launch).
__device__ float g_rwT[576 * 64];  // res_proj_w transposed: [p][c]
__device__ float g_dwT[576 * 6];   // data_proj_w transposed: [p][q]
__device__ float g_Ur[64 * 64];    // fixed-circuit unitary, real part [t][s]
__device__ float g_Ui[64 * 64];    // imag part [t][s]
__device__ float g_Zw[64 * 64];    // Zw[t][c] = sum_q out_proj_w[c,q]*sign_q(t)
__device__ float g_sang[48];       // style angles [b][q] (tanh*pi applied)
__device__ float g_cb[64];         // out_proj_b + res_proj_b

// ---------------------------------------------------------------------------
// Prep, 64-thread blocks (unchanged from R5-R9 — proven fast).
__global__ __launch_bounds__(64) void k_prep(
        const float* __restrict__ style,
        const float* __restrict__ dw, const float* __restrict__ rw,
        const float* __restrict__ s2dw, const float* __restrict__ s2db,
        const float* __restrict__ qcnn, const float* __restrict__ meas,
        const float* __restrict__ outw, const float* __restrict__ outb,
        const float* __restrict__ resb) {
    int bid = blockIdx.x;
    int t = threadIdx.x;

    if (bid >= 66) {  // transposes
        int i = (bid - 66) * 64 + t;  // 0..36863
        if (i < 576 * 6) { int q = i / 576, p = i % 576; g_dwT[p * 6 + q] = dw[i]; }
        { int c = i / 576, p = i % 576; g_rwT[p * 64 + c] = rw[i]; }
        return;
    }
    if (bid == 0) {  // Zw row t + combined bias
        float zr[6];
#pragma unroll
        for (int q = 0; q < 6; ++q) zr[q] = ((t >> (5 - q)) & 1) ? -1.f : 1.f;
#pragma unroll 8
        for (int c = 0; c < 64; ++c) {
            float z = 0.f;
#pragma unroll
            for (int q = 0; q < 6; ++q) z += outw[c * 6 + q] * zr[q];
            g_Zw[t * 64 + c] = z;
        }
        g_cb[t] = outb[t] + resb[t];
        return;
    }
    if (bid == 1) {  // style angles [b][q]
        if (t < 48) {
            int bb = t / 6, q = t % 6;
            float a = s2db[q];
#pragma unroll 8
            for (int j = 0; j < 128; ++j) a += style[bb * 128 + j] * s2dw[q * 128 + j];
            g_sang[t] = tanhf(a) * PI_F;
        }
        return;
    }

    // Circuit column s: lane t holds amplitude of basis state t (wire q = bit 5-q).
    int s = bid - 2;
    float ar = (t == s) ? 1.f : 0.f;
    float ai = 0.f;

#pragma unroll
    for (int l = 0; l < 2; ++l) {
#pragma unroll
        for (int wq = 0; wq < 6; ++wq) {
            int mask = 1 << (5 - wq);
            bool hi = (t & mask) != 0;
            float th = qcnn[((l * 6 + wq) * 2 + 0) * 3];
            float sg, cg; sincosf(0.5f * th, &sg, &cg);
            float pr = __shfl_xor(ar, mask);
            float pi2 = __shfl_xor(ai, mask);
            ar = hi ? (sg * pr + cg * ar) : (cg * ar - sg * pr);
            ai = hi ? (sg * pi2 + cg * ai) : (cg * ai - sg * pi2);
            float ph = qcnn[((l * 6 + wq) * 2 + 1) * 3];
            float sz, cz; sincosf(0.5f * ph, &sz, &cz);
            float szz = hi ? sz : -sz;
            float nr = cz * ar - szz * ai;
            float ni = cz * ai + szz * ar;
            ar = nr; ai = ni;
        }
#pragma unroll
        for (int wq = 0; wq < 6; ++wq) {  // ring CNOTs
            int cm = 1 << (5 - wq);
            int tm = 1 << (5 - ((wq + 1) % 6));
            float pr = __shfl_xor(ar, tm);
            float pi2 = __shfl_xor(ai, tm);
            if (t & cm) { ar = pr; ai = pi2; }
        }
    }
#pragma unroll
    for (int wq = 0; wq < 6; ++wq) {  // U3 measurement basis
        int mask = 1 << (5 - wq);
        bool hi = (t & mask) != 0;
        float th = meas[wq * 3 + 0], ph = meas[wq * 3 + 1], lm = meas[wq * 3 + 2];
        float st2, ct; sincosf(0.5f * th, &st2, &ct);
        float sl, cl;  sincosf(lm, &sl, &cl);
        float sp, cp;  sincosf(ph, &sp, &cp);
        float spl, cpl; sincosf(ph + lm, &spl, &cpl);
        float u01r = -cl * st2, u01i = -sl * st2;
        float u10r =  cp * st2, u10i =  sp * st2;
        float u11r =  cpl * ct, u11i =  spl * ct;
        float pr = __shfl_xor(ar, mask);
        float pi2 = __shfl_xor(ai, mask);
        float nr, ni;
        if (hi) {
            nr = u10r * pr - u10i * pi2 + u11r * ar - u11i * ai;
            ni = u10r * pi2 + u10i * pr + u11r * ai + u11i * ar;
        } else {
            nr = ct * ar + u01r * pr - u01i * pi2;
            ni = ct * ai + u01r * pi2 + u01i * pr;
        }
        ar = nr; ai = ni;
    }
    g_Ur[t * 64 + s] = ar;
    g_Ui[t * 64 + s] = ai;
}

// ---------------------------------------------------------------------------
// Main: 1024 threads = 64 pixels (lane==w) x 16 waves. wave wid: slice=wid&7
// (output chans/states [8s,8s+8)), khalf=wid>>3 (input chans [32k,32k+32)).
// x-tile (64ch x 3rows x 66w, halo-zeroed) staged ONCE into smem, then the
// conv reads LDS (ds_read latency hidden by 24-FMA windows). Phase buffers
// (ang / acc-park / psi / prob) overlay the dead x-tile region.
__global__ __launch_bounds__(1024, 4) void k_main(const float* __restrict__ x,
                                                  const float* __restrict__ dpb,
                                                  float* __restrict__ out) {
    // 12672 floats = 50688 B.
    // Phase A: xs[(row*64+c)*66 + 1 + w]            (12672)
    // Phase B: ang[q*1024+tid] (6144) | accP at 6144 + pix*65+c (4160)
    // Phase C: psi at 0 + pix*65+s (4160) | prob at 4160 + pix*65+t (4160)
    __shared__ float smem[12672];

    int tid  = threadIdx.x;
    int lane = tid & 63;                 // pixel within block (== w)
    int wid  = __builtin_amdgcn_readfirstlane(tid >> 6);  // 0..15
    int slice = wid & 7;
    int khalf = wid >> 3;
    int c0 = slice * 8;

    int p = blockIdx.x * 64 + lane;      // pixel id: b*4096 + h*64 + w
    int b = p >> 12;
    int h = (p >> 6) & 63;
    int w = p & 63;
    const float* xb = x + (b << 18);

    // ---- stage x-tile: zero 384 halo slots, load 12288 floats (12/thread)
    if (tid < 384) smem[(tid >> 1) * 66 + (tid & 1) * 65] = 0.f;
#pragma unroll
    for (int k = 0; k < 12; ++k) {
        int flat = k * 1024 + tid;       // 0..12287
        int row  = flat >> 12;
        int rem  = flat & 4095;
        int c    = rem >> 6;
        int w2   = rem & 63;
        int hh   = h + row - 1;
        float v = 0.f;
        if ((unsigned)hh < 64u) v = xb[(c << 12) + (hh << 6) + w2];
        smem[(row * 64 + c) * 66 + 1 + w2] = v;
    }
    __syncthreads();

    // ---- conv from LDS: window reuse, 24 FMAs per (c,row) (R4-proven body)
    float acc[8];
#pragma unroll
    for (int k = 0; k < 8; ++k) acc[k] = 0.f;
    int cb = khalf * 32;
#pragma unroll
    for (int i = 0; i < 3; ++i) {
#pragma unroll 4
        for (int cc = 0; cc < 32; ++cc) {
            int c = cb + cc;
            const float* xr = &smem[(i * 64 + c) * 66 + w];
            float vl = xr[0], vm = xr[1], vr = xr[2];
            const float* wp = g_rwT + ((c * 9 + i * 3) << 6) + c0;
            const float4 a0 = *(const float4*)(wp);
            const float4 a1 = *(const float4*)(wp + 4);
            const float4 b0 = *(const float4*)(wp + 64);
            const float4 b1 = *(const float4*)(wp + 68);
            const float4 d0 = *(const float4*)(wp + 128);
            const float4 d1 = *(const float4*)(wp + 132);
            acc[0] += vl * a0.x + vm * b0.x + vr * d0.x;
            acc[1] += vl * a0.y + vm * b0.y + vr * d0.y;
            acc[2] += vl * a0.z + vm * b0.z + vr * d0.z;
            acc[3] += vl * a0.w + vm * b0.w + vr * d0.w;
            acc[4] += vl * a1.x + vm * b1.x + vr * d1.x;
            acc[5] += vl * a1.y + vm * b1.y + vr * d1.y;
            acc[6] += vl * a1.z + vm * b1.z + vr * d1.z;
            acc[7] += vl * a1.w + vm * b1.w + vr * d1.w;
        }
    }

    // ---- angle partials for this wave's 4 channels (from LDS, post-conv)
    float ang[6] = {0.f, 0.f, 0.f, 0.f, 0.f, 0.f};
    int ca = wid * 4;
#pragma unroll
    for (int ci = 0; ci < 4; ++ci) {
        int c = ca + ci;
#pragma unroll
        for (int i = 0; i < 3; ++i) {
            const float* xr = &smem[(i * 64 + c) * 66 + w];
            float vl = xr[0], vm = xr[1], vr = xr[2];
            const float* dp = g_dwT + (c * 9 + i * 3) * 6;
#pragma unroll
            for (int q = 0; q < 6; ++q)
                ang[q] += vl * dp[q] + vm * dp[6 + q] + vr * dp[12 + q];
        }
    }
    __syncthreads();  // xs dead

    // ---- phase B: publish angle partials + khalf=1 conv partial
#pragma unroll
    for (int q = 0; q < 6; ++q) smem[q * 1024 + tid] = ang[q];
    if (khalf) {
#pragma unroll
        for (int k = 0; k < 8; ++k) smem[6144 + lane * 65 + c0 + k] = acc[k];
    }
    __syncthreads();
    if (!khalf) {
#pragma unroll
        for (int k = 0; k < 8; ++k) acc[k] += smem[6144 + lane * 65 + c0 + k];
    }
    float sc[6], co[6];
#pragma unroll
    for (int q = 0; q < 6; ++q) {
        float t = 0.f;
#pragma unroll
        for (int g2 = 0; g2 < 16; ++g2) t += smem[q * 1024 + g2 * 64 + lane];
        float theta = tanhf(t + dpb[q]) * PI_F + g_sang[b * 6 + q];
        sincosf(0.5f * theta, &sc[q], &co[q]);
    }
    __syncthreads();  // phase B dead

    // ---- phase C: psi (this wave's 4 states, 6-factor products)
#pragma unroll
    for (int ti = 0; ti < 4; ++ti) {
        int s = wid * 4 + ti;
        float v = ((s >> 5) & 1) ? sc[0] : co[0];
        v *= ((s >> 4) & 1) ? sc[1] : co[1];
        v *= ((s >> 3) & 1) ? sc[2] : co[2];
        v *= ((s >> 2) & 1) ? sc[3] : co[3];
        v *= ((s >> 1) & 1) ? sc[4] : co[4];
        v *= (s & 1)        ? sc[5] : co[5];
        smem[lane * 65 + s] = v;
    }
    __syncthreads();

    // ---- probs for this wave's 4 states: stream psi from LDS in blocks of 8
    int t0 = wid * 4;
    float yr[4], yi[4];
#pragma unroll
    for (int t = 0; t < 4; ++t) { yr[t] = 0.f; yi[t] = 0.f; }
#pragma unroll
    for (int s0 = 0; s0 < 8; ++s0) {
        float ps[8];
#pragma unroll
        for (int k = 0; k < 8; ++k) ps[k] = smem[lane * 65 + s0 * 8 + k];
#pragma unroll
        for (int t = 0; t < 4; ++t) {
            const float4 u0 = *(const float4*)(g_Ur + ((t0 + t) << 6) + s0 * 8);
            const float4 u1 = *(const float4*)(g_Ur + ((t0 + t) << 6) + s0 * 8 + 4);
            const float4 v0 = *(const float4*)(g_Ui + ((t0 + t) << 6) + s0 * 8);
            const float4 v1 = *(const float4*)(g_Ui + ((t0 + t) << 6) + s0 * 8 + 4);
            yr[t] += u0.x * ps[0] + u0.y * ps[1] + u0.z * ps[2] + u0.w * ps[3]
                   + u1.x * ps[4] + u1.y * ps[5] + u1.z * ps[6] + u1.w * ps[7];
            yi[t] += v0.x * ps[0] + v0.y * ps[1] + v0.z * ps[2] + v0.w * ps[3]
                   + v1.x * ps[4] + v1.y * ps[5] + v1.z * ps[6] + v1.w * ps[7];
        }
    }
#pragma unroll
    for (int t = 0; t < 4; ++t)
        smem[4160 + lane * 65 + t0 + t] = yr[t] * yr[t] + yi[t] * yi[t];
    __syncthreads();

    // ---- khalf=0 folds probs through Zw into its 8 output channels + stores
    if (!khalf) {
#pragma unroll 8
        for (int t = 0; t < 64; ++t) {
            float pr = smem[4160 + lane * 65 + t];
            const float4 z0 = *(const float4*)(g_Zw + (t << 6) + c0);
            const float4 z1 = *(const float4*)(g_Zw + (t << 6) + c0 + 4);
            acc[0] += pr * z0.x; acc[1] += pr * z0.y;
            acc[2] += pr * z0.z; acc[3] += pr * z0.w;
            acc[4] += pr * z1.x; acc[5] += pr * z1.y;
            acc[6] += pr * z1.z; acc[7] += pr * z1.w;
        }
        int ob = (b << 18) + (h << 6) + w;
#pragma unroll
        for (int k = 0; k < 8; ++k) {
            out[ob + ((c0 + k) << 12)] = acc[k] + g_cb[c0 + k];
        }
    }
}

// ---------------------------------------------------------------------------
extern "C" void kernel_launch(void* const* d_in, const int* in_sizes, int n_in,
                              void* d_out, int out_size, void* d_ws, size_t ws_size,
                              hipStream_t stream) {
    const float* x     = (const float*)d_in[0];
    const float* style = (const float*)d_in[1];
    const float* dw    = (const float*)d_in[2];
    const float* dpb   = (const float*)d_in[3];
    const float* s2dw  = (const float*)d_in[4];
    const float* s2db  = (const float*)d_in[5];
    const float* qcnn  = (const float*)d_in[6];
    const float* meas  = (const float*)d_in[7];
    const float* outw  = (const float*)d_in[8];
    const float* outb  = (const float*)d_in[9];
    const float* rw    = (const float*)d_in[10];
    const float* resb  = (const float*)d_in[11];
    float* out = (float*)d_out;

    hipLaunchKernelGGL(k_prep, dim3(642), dim3(64), 0, stream,
                       style, dw, rw, s2dw, s2db, qcnn, meas, outw, outb, resb);
    hipLaunchKernelGGL(k_main, dim3(512), dim3(1024), 0, stream, x, dpb, out);
}

// Round 11
// 120.503 us; speedup vs baseline: 1.6200x; 1.3478x over previous
//
#include <hip/hip_runtime.h>
#include <math.h>

#define PI_F 3.14159265358979323846f

typedef __attribute__((ext_vector_type(8))) short bf16x8;   // 8 bf16 (4 VGPRs)
typedef __attribute__((ext_vector_type(4))) float f32x4;    // MFMA C/D

// Persistent device scratch (rewritten fully on every launch).
__device__ float g_Ur[64 * 64];    // fixed-circuit unitary, real part [t][s]
__device__ float g_Ui[64 * 64];    // imag part [t][s]
__device__ float g_Zw[64 * 64];    // Zw[t][c] = sum_q out_proj_w[c,q]*sign_q(t)
__device__ float g_sang[48];       // style angles [b][q] (tanh*pi applied)
__device__ float g_cb[64];         // out_proj_b + res_proj_b
// MFMA B operand, bf16: [ntile(5)][slab(18)][lane(64)][j(8)]
// n = nt*16 + (lane&15); k_local = (lane>>4)*8 + j; k_perm = slab*32 + k_local;
// k_perm -> (ij = slab>>1, c = (slab&1)*32 + k_local); k_orig = c*9 + ij.
__device__ __attribute__((aligned(16))) unsigned short g_Bm[5 * 18 * 64 * 8];

__device__ inline unsigned short bf16rne(float f) {
    unsigned u = __float_as_uint(f);
    return (unsigned short)((u + 0x7FFFu + ((u >> 16) & 1u)) >> 16);
}

// ---------------------------------------------------------------------------
// Prep, 64-thread blocks.
//   bid 0      : Zw + combined bias
//   bid 1      : style angles
//   bid 2..65  : circuit column s = bid-2 (wave butterfly via __shfl_xor)
//   bid 66..155: Bm build (5760 lane-entries, 64 per block)
__global__ __launch_bounds__(64) void k_prep(
        const float* __restrict__ style,
        const float* __restrict__ dw, const float* __restrict__ rw,
        const float* __restrict__ s2dw, const float* __restrict__ s2db,
        const float* __restrict__ qcnn, const float* __restrict__ meas,
        const float* __restrict__ outw, const float* __restrict__ outb,
        const float* __restrict__ resb) {
    int bid = blockIdx.x;
    int t = threadIdx.x;

    if (bid >= 66) {  // Bm build
        int entry = (bid - 66) * 64 + t;          // 0..5759
        int nt   = entry / 1152;
        int rem  = entry - nt * 1152;
        int slab = rem >> 6;
        int ln   = rem & 63;
        int m    = ln & 15, quad = ln >> 4;
        int n    = nt * 16 + m;
        int ij   = slab >> 1;
        int ch   = (slab & 1) * 32;
#pragma unroll
        for (int j = 0; j < 8; ++j) {
            int c = ch + quad * 8 + j;
            int ko = c * 9 + ij;
            float v = 0.f;
            if (n < 64)      v = rw[n * 576 + ko];
            else if (n < 70) v = dw[(n - 64) * 576 + ko];
            g_Bm[entry * 8 + j] = bf16rne(v);
        }
        return;
    }
    if (bid == 0) {  // Zw row t + combined bias
        float zr[6];
#pragma unroll
        for (int q = 0; q < 6; ++q) zr[q] = ((t >> (5 - q)) & 1) ? -1.f : 1.f;
#pragma unroll 8
        for (int c = 0; c < 64; ++c) {
            float z = 0.f;
#pragma unroll
            for (int q = 0; q < 6; ++q) z += outw[c * 6 + q] * zr[q];
            g_Zw[t * 64 + c] = z;
        }
        g_cb[t] = outb[t] + resb[t];
        return;
    }
    if (bid == 1) {  // style angles [b][q]
        if (t < 48) {
            int bb = t / 6, q = t % 6;
            float a = s2db[q];
#pragma unroll 8
            for (int j = 0; j < 128; ++j) a += style[bb * 128 + j] * s2dw[q * 128 + j];
            g_sang[t] = tanhf(a) * PI_F;
        }
        return;
    }

    // Circuit column s: lane t holds amplitude of basis state t (wire q = bit 5-q).
    int s = bid - 2;
    float ar = (t == s) ? 1.f : 0.f;
    float ai = 0.f;

#pragma unroll
    for (int l = 0; l < 2; ++l) {
#pragma unroll
        for (int wq = 0; wq < 6; ++wq) {
            int mask = 1 << (5 - wq);
            bool hi = (t & mask) != 0;
            float th = qcnn[((l * 6 + wq) * 2 + 0) * 3];
            float sg, cg; sincosf(0.5f * th, &sg, &cg);
            float pr = __shfl_xor(ar, mask);
            float pi2 = __shfl_xor(ai, mask);
            ar = hi ? (sg * pr + cg * ar) : (cg * ar - sg * pr);
            ai = hi ? (sg * pi2 + cg * ai) : (cg * ai - sg * pi2);
            float ph = qcnn[((l * 6 + wq) * 2 + 1) * 3];
            float sz, cz; sincosf(0.5f * ph, &sz, &cz);
            float szz = hi ? sz : -sz;
            float nr = cz * ar - szz * ai;
            float ni = cz * ai + szz * ar;
            ar = nr; ai = ni;
        }
#pragma unroll
        for (int wq = 0; wq < 6; ++wq) {  // ring CNOTs
            int cm = 1 << (5 - wq);
            int tm = 1 << (5 - ((wq + 1) % 6));
            float pr = __shfl_xor(ar, tm);
            float pi2 = __shfl_xor(ai, tm);
            if (t & cm) { ar = pr; ai = pi2; }
        }
    }
#pragma unroll
    for (int wq = 0; wq < 6; ++wq) {  // U3 measurement basis
        int mask = 1 << (5 - wq);
        bool hi = (t & mask) != 0;
        float th = meas[wq * 3 + 0], ph = meas[wq * 3 + 1], lm = meas[wq * 3 + 2];
        float st2, ct; sincosf(0.5f * th, &st2, &ct);
        float sl, cl;  sincosf(lm, &sl, &cl);
        float sp, cp;  sincosf(ph, &sp, &cp);
        float spl, cpl; sincosf(ph + lm, &spl, &cpl);
        float u01r = -cl * st2, u01i = -sl * st2;
        float u10r =  cp * st2, u10i =  sp * st2;
        float u11r =  cpl * ct, u11i =  spl * ct;
        float pr = __shfl_xor(ar, mask);
        float pi2 = __shfl_xor(ai, mask);
        float nr, ni;
        if (hi) {
            nr = u10r * pr - u10i * pi2 + u11r * ar - u11i * ai;
            ni = u10r * pi2 + u10i * pr + u11r * ai + u11i * ar;
        } else {
            nr = ct * ar + u01r * pr - u01i * pi2;
            ni = ct * ai + u01r * pi2 + u01i * pr;
        }
        ar = nr; ai = ni;
    }
    g_Ur[t * 64 + s] = ar;
    g_Ui[t * 64 + s] = ai;
}

// ---------------------------------------------------------------------------
// Main: 1024 threads = 64 pixels (lane==w) x 16 waves.
// Conv+angle GEMM on MFMA: C[64 pix][80] = A[64][576]_bf16 @ B[576][80]_bf16.
// 20 16x16 tiles over 16 waves (waves 0-3 take a second tile). A from a
// c-contiguous bf16 x-tile in LDS (one ds_read_b128 per slab); B from g_Bm
// (coalesced dwordx4). Quantum epilogue identical to R10.
// smem plan (floats): [0,4160) psi | [4160,8320) prob | [8320,13504) convres
//   (64x81); staging xs (bf16 [3][66][72] = 28512 B) overlays [0,7128) uints.
__global__ __launch_bounds__(1024, 4) void k_main(const float* __restrict__ x,
                                                  const float* __restrict__ dpb,
                                                  float* __restrict__ out) {
    __shared__ __attribute__((aligned(16))) float smem[13504];  // 54016 B
    unsigned*       xsu32 = (unsigned*)smem;
    const unsigned short* xsu = (const unsigned short*)smem;
    float*          convres = smem + 8320;                      // [pix][81]

    int tid  = threadIdx.x;
    int lane = tid & 63;                 // pixel within block (== w)
    int wid  = __builtin_amdgcn_readfirstlane(tid >> 6);  // 0..15
    int m    = lane & 15;
    int quad = lane >> 4;

    int p = blockIdx.x * 64 + lane;      // pixel id: b*4096 + h*64 + w
    int b = p >> 12;
    int h = (p >> 6) & 63;
    int w = p & 63;
    const float* xb = x + (b << 18);

    // ---- stage x-tile as bf16: xs[row][wp][c], wp = w+1 (halo cols 0,65).
    // ushort strides: c:1, wp:72, row:4752. Packed pair writes (c even).
    if (tid < 216) {  // zero halo: 3 rows x 2 cols x 36 uints
        int r3 = tid / 72, rest = tid % 72;
        int half = rest / 36, cp = rest % 36;
        xsu32[(r3 * 66 + half * 65) * 36 + cp] = 0u;
    }
#pragma unroll
    for (int k = 0; k < 6; ++k) {
        int flat = k * 1024 + tid;       // 0..6143 = 3 rows x 32 cpairs x 64 w
        int row  = flat >> 11;
        int rem  = flat & 2047;
        int cp   = rem >> 6;
        int w2   = rem & 63;
        int hh   = h + row - 1;
        float v0 = 0.f, v1 = 0.f;
        if ((unsigned)hh < 64u) {
            const float* px = xb + (hh << 6) + w2;
            v0 = px[(2 * cp) << 12];
            v1 = px[(2 * cp + 1) << 12];
        }
        xsu32[(row * 66 + w2 + 1) * 36 + cp] =
            (unsigned)bf16rne(v0) | ((unsigned)bf16rne(v1) << 16);
    }
    __syncthreads();

    // ---- MFMA GEMM. Tile assignment: wave wid -> (mt0=wid>>2, nt0=wid&3);
    // waves 0-3 also do (mt1=wid, nt1=4) (angle cols 64-69 + zero pad).
    int mt0 = wid >> 2, nt0 = wid & 3;
    const unsigned short* a0base = xsu + (mt0 * 16 + m) * 72 + quad * 8;
    const unsigned short* b0base = g_Bm + ((nt0 * 18) * 64 + lane) * 8;
    f32x4 acc0 = {0.f, 0.f, 0.f, 0.f};
    f32x4 acc1 = {0.f, 0.f, 0.f, 0.f};
    if (wid < 4) {
        const unsigned short* a1base = xsu + (wid * 16 + m) * 72 + quad * 8;
        const unsigned short* b1base = g_Bm + ((4 * 18) * 64 + lane) * 8;
#pragma unroll
        for (int slab = 0; slab < 18; ++slab) {
            int ij = slab >> 1, i = ij / 3, j = ij - 3 * (ij / 3);
            int aoff = i * 4752 + j * 72 + (slab & 1) * 32;
            bf16x8 a0 = *(const bf16x8*)(a0base + aoff);
            bf16x8 b0 = *(const bf16x8*)(b0base + slab * 512);
            acc0 = __builtin_amdgcn_mfma_f32_16x16x32_bf16(a0, b0, acc0, 0, 0, 0);
            bf16x8 a1 = *(const bf16x8*)(a1base + aoff);
            bf16x8 b1 = *(const bf16x8*)(b1base + slab * 512);
            acc1 = __builtin_amdgcn_mfma_f32_16x16x32_bf16(a1, b1, acc1, 0, 0, 0);
        }
    } else {
#pragma unroll
        for (int slab = 0; slab < 18; ++slab) {
            int ij = slab >> 1, i = ij / 3, j = ij - 3 * (ij / 3);
            int aoff = i * 4752 + j * 72 + (slab & 1) * 32;
            bf16x8 a0 = *(const bf16x8*)(a0base + aoff);
            bf16x8 b0 = *(const bf16x8*)(b0base + slab * 512);
            acc0 = __builtin_amdgcn_mfma_f32_16x16x32_bf16(a0, b0, acc0, 0, 0, 0);
        }
    }
    // C/D layout (verified): col = lane&15 (=n), row = quad*4 + reg (=pixel).
#pragma unroll
    for (int r = 0; r < 4; ++r) {
        convres[(mt0 * 16 + quad * 4 + r) * 81 + nt0 * 16 + m] = acc0[r];
    }
    if (wid < 4) {
#pragma unroll
        for (int r = 0; r < 4; ++r) {
            convres[(wid * 16 + quad * 4 + r) * 81 + 64 + m] = acc1[r];
        }
    }
    __syncthreads();

    // ---- theta from angle columns, sincos
    float sc[6], co[6];
#pragma unroll
    for (int q = 0; q < 6; ++q) {
        float t = convres[lane * 81 + 64 + q];
        float theta = tanhf(t + dpb[q]) * PI_F + g_sang[b * 6 + q];
        sincosf(0.5f * theta, &sc[q], &co[q]);
    }

    // ---- psi (this wave's 4 states, 6-factor products) -> smem[0..4160)
#pragma unroll
    for (int ti = 0; ti < 4; ++ti) {
        int s = wid * 4 + ti;
        float v = ((s >> 5) & 1) ? sc[0] : co[0];
        v *= ((s >> 4) & 1) ? sc[1] : co[1];
        v *= ((s >> 3) & 1) ? sc[2] : co[2];
        v *= ((s >> 2) & 1) ? sc[3] : co[3];
        v *= ((s >> 1) & 1) ? sc[4] : co[4];
        v *= (s & 1)        ? sc[5] : co[5];
        smem[lane * 65 + s] = v;
    }
    __syncthreads();

    // ---- probs for this wave's 4 states -> smem[4160..8320)
    int t0 = wid * 4;
    float yr[4], yi[4];
#pragma unroll
    for (int t = 0; t < 4; ++t) { yr[t] = 0.f; yi[t] = 0.f; }
#pragma unroll
    for (int s0 = 0; s0 < 8; ++s0) {
        float ps[8];
#pragma unroll
        for (int k = 0; k < 8; ++k) ps[k] = smem[lane * 65 + s0 * 8 + k];
#pragma unroll
        for (int t = 0; t < 4; ++t) {
            const float4 u0 = *(const float4*)(g_Ur + ((t0 + t) << 6) + s0 * 8);
            const float4 u1 = *(const float4*)(g_Ur + ((t0 + t) << 6) + s0 * 8 + 4);
            const float4 v0 = *(const float4*)(g_Ui + ((t0 + t) << 6) + s0 * 8);
            const float4 v1 = *(const float4*)(g_Ui + ((t0 + t) << 6) + s0 * 8 + 4);
            yr[t] += u0.x * ps[0] + u0.y * ps[1] + u0.z * ps[2] + u0.w * ps[3]
                   + u1.x * ps[4] + u1.y * ps[5] + u1.z * ps[6] + u1.w * ps[7];
            yi[t] += v0.x * ps[0] + v0.y * ps[1] + v0.z * ps[2] + v0.w * ps[3]
                   + v1.x * ps[4] + v1.y * ps[5] + v1.z * ps[6] + v1.w * ps[7];
        }
    }
#pragma unroll
    for (int t = 0; t < 4; ++t)
        smem[4160 + lane * 65 + t0 + t] = yr[t] * yr[t] + yi[t] * yi[t];
    __syncthreads();

    // ---- waves 0-7: fold probs through Zw into 8 output channels + store
    if (wid < 8) {
        int c0 = wid * 8;
        float acc[8];
#pragma unroll
        for (int k = 0; k < 8; ++k) acc[k] = convres[lane * 81 + c0 + k];
#pragma unroll 8
        for (int t = 0; t < 64; ++t) {
            float pr = smem[4160 + lane * 65 + t];
            const float4 z0 = *(const float4*)(g_Zw + (t << 6) + c0);
            const float4 z1 = *(const float4*)(g_Zw + (t << 6) + c0 + 4);
            acc[0] += pr * z0.x; acc[1] += pr * z0.y;
            acc[2] += pr * z0.z; acc[3] += pr * z0.w;
            acc[4] += pr * z1.x; acc[5] += pr * z1.y;
            acc[6] += pr * z1.z; acc[7] += pr * z1.w;
        }
        int ob = (b << 18) + (h << 6) + w;
#pragma unroll
        for (int k = 0; k < 8; ++k) {
            out[ob + ((c0 + k) << 12)] = acc[k] + g_cb[c0 + k];
        }
    }
}

// ---------------------------------------------------------------------------
extern "C" void kernel_launch(void* const* d_in, const int* in_sizes, int n_in,
                              void* d_out, int out_size, void* d_ws, size_t ws_size,
                              hipStream_t stream) {
    const float* x     = (const float*)d_in[0];
    const float* style = (const float*)d_in[1];
    const float* dw    = (const float*)d_in[2];
    const float* dpb   = (const float*)d_in[3];
    const float* s2dw  = (const float*)d_in[4];
    const float* s2db  = (const float*)d_in[5];
    const float* qcnn  = (const float*)d_in[6];
    const float* meas  = (const float*)d_in[7];
    const float* outw  = (const float*)d_in[8];
    const float* outb  = (const float*)d_in[9];
    const float* rw    = (const float*)d_in[10];
    const float* resb  = (const float*)d_in[11];
    float* out = (float*)d_out;

    hipLaunchKernelGGL(k_prep, dim3(156), dim3(64), 0, stream,
                       style, dw, rw, s2dw, s2db, qcnn, meas, outw, outb, resb);
    hipLaunchKernelGGL(k_main, dim3(512), dim3(1024), 0, stream, x, dpb, out);
}

// Round 12
// 109.027 us; speedup vs baseline: 1.7905x; 1.1053x over previous
//
#include <hip/hip_runtime.h>
#include <math.h>

#define PI_F 3.14159265358979323846f

typedef __attribute__((ext_vector_type(8))) short bf16x8;   // 8 bf16 (4 VGPRs)
typedef __attribute__((ext_vector_type(4))) float f32x4;    // MFMA C/D

// Persistent device scratch (rewritten fully on every launch).
__device__ float g_sang[48];       // style angles [b][q] (tanh*pi applied)
__device__ float g_cb[64];         // out_proj_b + res_proj_b
// bf16 operand tables for the epilogue GEMMs:
__device__ __attribute__((aligned(16))) unsigned short g_Urb[64 * 64];  // [t][s]
__device__ __attribute__((aligned(16))) unsigned short g_Uib[64 * 64];  // [t][s]
__device__ __attribute__((aligned(16))) unsigned short g_Zwc[64 * 64];  // [c][t]
// MFMA B operand for the conv GEMM (R11 layout, proven):
// [ntile(5)][slab(18)][lane(64)][j(8)]
__device__ __attribute__((aligned(16))) unsigned short g_Bm[5 * 18 * 64 * 8];

__device__ inline unsigned short bf16rne(float f) {
    unsigned u = __float_as_uint(f);
    return (unsigned short)((u + 0x7FFFu + ((u >> 16) & 1u)) >> 16);
}

// ---------------------------------------------------------------------------
// Prep, 64-thread blocks.
//   bid 0      : Zw (transposed bf16) + combined bias
//   bid 1      : style angles
//   bid 2..65  : circuit column s = bid-2 (wave butterfly via __shfl_xor)
//   bid 66..155: Bm build (5760 lane-entries, 64 per block)
__global__ __launch_bounds__(64) void k_prep(
        const float* __restrict__ style,
        const float* __restrict__ dw, const float* __restrict__ rw,
        const float* __restrict__ s2dw, const float* __restrict__ s2db,
        const float* __restrict__ qcnn, const float* __restrict__ meas,
        const float* __restrict__ outw, const float* __restrict__ outb,
        const float* __restrict__ resb) {
    int bid = blockIdx.x;
    int t = threadIdx.x;

    if (bid >= 66) {  // Bm build (verbatim R11)
        int entry = (bid - 66) * 64 + t;          // 0..5759
        int nt   = entry / 1152;
        int rem  = entry - nt * 1152;
        int slab = rem >> 6;
        int ln   = rem & 63;
        int m    = ln & 15, quad = ln >> 4;
        int n    = nt * 16 + m;
        int ij   = slab >> 1;
        int ch   = (slab & 1) * 32;
#pragma unroll
        for (int j = 0; j < 8; ++j) {
            int c = ch + quad * 8 + j;
            int ko = c * 9 + ij;
            float v = 0.f;
            if (n < 64)      v = rw[n * 576 + ko];
            else if (n < 70) v = dw[(n - 64) * 576 + ko];
            g_Bm[entry * 8 + j] = bf16rne(v);
        }
        return;
    }
    if (bid == 0) {  // Zw (store transposed bf16: [c][t]) + combined bias
        float zr[6];
#pragma unroll
        for (int q = 0; q < 6; ++q) zr[q] = ((t >> (5 - q)) & 1) ? -1.f : 1.f;
#pragma unroll 8
        for (int c = 0; c < 64; ++c) {
            float z = 0.f;
#pragma unroll
            for (int q = 0; q < 6; ++q) z += outw[c * 6 + q] * zr[q];
            g_Zwc[c * 64 + t] = bf16rne(z);   // row t of Zw -> column t of Zwc
        }
        g_cb[t] = outb[t] + resb[t];
        return;
    }
    if (bid == 1) {  // style angles [b][q]
        if (t < 48) {
            int bb = t / 6, q = t % 6;
            float a = s2db[q];
#pragma unroll 8
            for (int j = 0; j < 128; ++j) a += style[bb * 128 + j] * s2dw[q * 128 + j];
            g_sang[t] = tanhf(a) * PI_F;
        }
        return;
    }

    // Circuit column s: lane t holds amplitude of basis state t (wire q = bit 5-q).
    int s = bid - 2;
    float ar = (t == s) ? 1.f : 0.f;
    float ai = 0.f;

#pragma unroll
    for (int l = 0; l < 2; ++l) {
#pragma unroll
        for (int wq = 0; wq < 6; ++wq) {
            int mask = 1 << (5 - wq);
            bool hi = (t & mask) != 0;
            float th = qcnn[((l * 6 + wq) * 2 + 0) * 3];
            float sg, cg; sincosf(0.5f * th, &sg, &cg);
            float pr = __shfl_xor(ar, mask);
            float pi2 = __shfl_xor(ai, mask);
            ar = hi ? (sg * pr + cg * ar) : (cg * ar - sg * pr);
            ai = hi ? (sg * pi2 + cg * ai) : (cg * ai - sg * pi2);
            float ph = qcnn[((l * 6 + wq) * 2 + 1) * 3];
            float sz, cz; sincosf(0.5f * ph, &sz, &cz);
            float szz = hi ? sz : -sz;
            float nr = cz * ar - szz * ai;
            float ni = cz * ai + szz * ar;
            ar = nr; ai = ni;
        }
#pragma unroll
        for (int wq = 0; wq < 6; ++wq) {  // ring CNOTs
            int cm = 1 << (5 - wq);
            int tm = 1 << (5 - ((wq + 1) % 6));
            float pr = __shfl_xor(ar, tm);
            float pi2 = __shfl_xor(ai, tm);
            if (t & cm) { ar = pr; ai = pi2; }
        }
    }
#pragma unroll
    for (int wq = 0; wq < 6; ++wq) {  // U3 measurement basis
        int mask = 1 << (5 - wq);
        bool hi = (t & mask) != 0;
        float th = meas[wq * 3 + 0], ph = meas[wq * 3 + 1], lm = meas[wq * 3 + 2];
        float st2, ct; sincosf(0.5f * th, &st2, &ct);
        float sl, cl;  sincosf(lm, &sl, &cl);
        float sp, cp;  sincosf(ph, &sp, &cp);
        float spl, cpl; sincosf(ph + lm, &spl, &cpl);
        float u01r = -cl * st2, u01i = -sl * st2;
        float u10r =  cp * st2, u10i =  sp * st2;
        float u11r =  cpl * ct, u11i =  spl * ct;
        float pr = __shfl_xor(ar, mask);
        float pi2 = __shfl_xor(ai, mask);
        float nr, ni;
        if (hi) {
            nr = u10r * pr - u10i * pi2 + u11r * ar - u11i * ai;
            ni = u10r * pi2 + u10i * pr + u11r * ai + u11i * ar;
        } else {
            nr = ct * ar + u01r * pr - u01i * pi2;
            ni = ct * ai + u01r * pi2 + u01i * pr;
        }
        ar = nr; ai = ni;
    }
    g_Urb[t * 64 + s] = bf16rne(ar);
    g_Uib[t * 64 + s] = bf16rne(ai);
}

// ---------------------------------------------------------------------------
// Main: 1024 threads = 64 pixels (lane==w) x 16 waves.
// Phase 1: conv+angle GEMM on MFMA (verbatim R11).
// Phase 2: quantum epilogue on MFMA: Yr/Yi = psi @ U^T (bf16), P = Yr^2+Yi^2,
//          O = P @ Zw, accumulated into convres; coalesced store.
// smem plan (floats):
//   [0,7128)      xs staging (bf16 [3][66][72])        -- dead after conv GEMM
//   [0,768)       fact[12][64]    (phase B)
//   [1024,3328)   psi_bf [64][72] ushort (phase B)
//   [3328,5632)   p_bf   [64][72] ushort (phase B)
//   [8320,13504)  convres [64][81] fp32 (persists)
__global__ __launch_bounds__(1024, 4) void k_main(const float* __restrict__ x,
                                                  const float* __restrict__ dpb,
                                                  float* __restrict__ out) {
    __shared__ __attribute__((aligned(16))) float smem[13504];  // 54016 B
    unsigned*             xsu32 = (unsigned*)smem;
    const unsigned short* xsu   = (const unsigned short*)smem;
    float*          convres = smem + 8320;                      // [pix][81]
    float*          fact    = smem;                             // [12][64]
    unsigned short* psi_bf  = (unsigned short*)(smem + 1024);   // [64][72]
    unsigned short* p_bf    = (unsigned short*)(smem + 3328);   // [64][72]

    int tid  = threadIdx.x;
    int lane = tid & 63;                 // pixel within block (== w)
    int wid  = __builtin_amdgcn_readfirstlane(tid >> 6);  // 0..15
    int m    = lane & 15;
    int quad = lane >> 4;

    int p = blockIdx.x * 64 + lane;      // pixel id: b*4096 + h*64 + w
    int b = p >> 12;
    int h = (p >> 6) & 63;
    int w = p & 63;
    const float* xb = x + (b << 18);

    // ---- stage x-tile as bf16 (verbatim R11)
    if (tid < 216) {  // zero halo: 3 rows x 2 cols x 36 uints
        int r3 = tid / 72, rest = tid % 72;
        int half = rest / 36, cp = rest % 36;
        xsu32[(r3 * 66 + half * 65) * 36 + cp] = 0u;
    }
#pragma unroll
    for (int k = 0; k < 6; ++k) {
        int flat = k * 1024 + tid;       // 0..6143 = 3 rows x 32 cpairs x 64 w
        int row  = flat >> 11;
        int rem  = flat & 2047;
        int cp   = rem >> 6;
        int w2   = rem & 63;
        int hh   = h + row - 1;
        float v0 = 0.f, v1 = 0.f;
        if ((unsigned)hh < 64u) {
            const float* px = xb + (hh << 6) + w2;
            v0 = px[(2 * cp) << 12];
            v1 = px[(2 * cp + 1) << 12];
        }
        xsu32[(row * 66 + w2 + 1) * 36 + cp] =
            (unsigned)bf16rne(v0) | ((unsigned)bf16rne(v1) << 16);
    }
    __syncthreads();

    // ---- conv+angle MFMA GEMM (verbatim R11)
    int mt0 = wid >> 2, nt0 = wid & 3;
    const unsigned short* a0base = xsu + (mt0 * 16 + m) * 72 + quad * 8;
    const unsigned short* b0base = g_Bm + ((nt0 * 18) * 64 + lane) * 8;
    f32x4 acc0 = {0.f, 0.f, 0.f, 0.f};
    f32x4 acc1 = {0.f, 0.f, 0.f, 0.f};
    if (wid < 4) {
        const unsigned short* a1base = xsu + (wid * 16 + m) * 72 + quad * 8;
        const unsigned short* b1base = g_Bm + ((4 * 18) * 64 + lane) * 8;
#pragma unroll
        for (int slab = 0; slab < 18; ++slab) {
            int ij = slab >> 1, i = ij / 3, j = ij - 3 * (ij / 3);
            int aoff = i * 4752 + j * 72 + (slab & 1) * 32;
            bf16x8 a0 = *(const bf16x8*)(a0base + aoff);
            bf16x8 b0 = *(const bf16x8*)(b0base + slab * 512);
            acc0 = __builtin_amdgcn_mfma_f32_16x16x32_bf16(a0, b0, acc0, 0, 0, 0);
            bf16x8 a1 = *(const bf16x8*)(a1base + aoff);
            bf16x8 b1 = *(const bf16x8*)(b1base + slab * 512);
            acc1 = __builtin_amdgcn_mfma_f32_16x16x32_bf16(a1, b1, acc1, 0, 0, 0);
        }
    } else {
#pragma unroll
        for (int slab = 0; slab < 18; ++slab) {
            int ij = slab >> 1, i = ij / 3, j = ij - 3 * (ij / 3);
            int aoff = i * 4752 + j * 72 + (slab & 1) * 32;
            bf16x8 a0 = *(const bf16x8*)(a0base + aoff);
            bf16x8 b0 = *(const bf16x8*)(b0base + slab * 512);
            acc0 = __builtin_amdgcn_mfma_f32_16x16x32_bf16(a0, b0, acc0, 0, 0, 0);
        }
    }
    // C/D layout (verified): col = lane&15 (=n), row = quad*4 + reg (=pixel).
#pragma unroll
    for (int r = 0; r < 4; ++r) {
        convres[(mt0 * 16 + quad * 4 + r) * 81 + nt0 * 16 + m] = acc0[r];
    }
    if (wid < 4) {
#pragma unroll
        for (int r = 0; r < 4; ++r) {
            convres[(wid * 16 + quad * 4 + r) * 81 + 64 + m] = acc1[r];
        }
    }
    __syncthreads();

    // ---- factors: waves 0-5 compute sincos(theta_q/2) for all 64 pixels
    if (wid < 6) {
        int q = wid;
        float t = convres[lane * 81 + 64 + q];
        float theta = tanhf(t + dpb[q]) * PI_F + g_sang[b * 6 + q];
        float sv, cv; sincosf(0.5f * theta, &sv, &cv);
        fact[q * 64 + lane] = sv;
        fact[(6 + q) * 64 + lane] = cv;
    }
    __syncthreads();

    // ---- psi (bf16): each wave builds states 4*wid..4*wid+3 for its pixel
    {
        float f0s = fact[0 * 64 + lane], f0c = fact[6 * 64 + lane];
        float f1s = fact[1 * 64 + lane], f1c = fact[7 * 64 + lane];
        float f2s = fact[2 * 64 + lane], f2c = fact[8 * 64 + lane];
        float f3s = fact[3 * 64 + lane], f3c = fact[9 * 64 + lane];
        float f4s = fact[4 * 64 + lane], f4c = fact[10 * 64 + lane];
        float f5s = fact[5 * 64 + lane], f5c = fact[11 * 64 + lane];
        int sb = wid * 4;
        // common high-bit prefix (bits 5..2 fixed across the 4 states)
        float pre = (((sb >> 5) & 1) ? f0s : f0c)
                  * (((sb >> 4) & 1) ? f1s : f1c)
                  * (((sb >> 3) & 1) ? f2s : f2c)
                  * (((sb >> 2) & 1) ? f3s : f3c);
        unsigned short pk[4];
#pragma unroll
        for (int ti = 0; ti < 4; ++ti) {
            float v = pre * ((ti & 2) ? f4s : f4c) * ((ti & 1) ? f5s : f5c);
            pk[ti] = bf16rne(v);
        }
        *(uint2*)(psi_bf + lane * 72 + sb) =
            make_uint2((unsigned)pk[0] | ((unsigned)pk[1] << 16),
                       (unsigned)pk[2] | ((unsigned)pk[3] << 16));
    }
    __syncthreads();

    // ---- GEMM 1/2: Yr/Yi[pix][t] = psi[pix][s] @ U[t][s]^T, tile (mt0,nt0)
    {
        const unsigned short* pa = psi_bf + (mt0 * 16 + m) * 72 + quad * 8;
        const unsigned short* ur = g_Urb + (nt0 * 16 + m) * 64 + quad * 8;
        const unsigned short* ui = g_Uib + (nt0 * 16 + m) * 64 + quad * 8;
        bf16x8 aA = *(const bf16x8*)(pa);
        bf16x8 aB = *(const bf16x8*)(pa + 32);
        f32x4 c1 = {0.f, 0.f, 0.f, 0.f};
        f32x4 c2 = {0.f, 0.f, 0.f, 0.f};
        c1 = __builtin_amdgcn_mfma_f32_16x16x32_bf16(aA, *(const bf16x8*)(ur), c1, 0, 0, 0);
        c1 = __builtin_amdgcn_mfma_f32_16x16x32_bf16(aB, *(const bf16x8*)(ur + 32), c1, 0, 0, 0);
        c2 = __builtin_amdgcn_mfma_f32_16x16x32_bf16(aA, *(const bf16x8*)(ui), c2, 0, 0, 0);
        c2 = __builtin_amdgcn_mfma_f32_16x16x32_bf16(aB, *(const bf16x8*)(ui + 32), c2, 0, 0, 0);
#pragma unroll
        for (int r = 0; r < 4; ++r) {
            float pv = c1[r] * c1[r] + c2[r] * c2[r];
            p_bf[(mt0 * 16 + quad * 4 + r) * 72 + nt0 * 16 + m] = bf16rne(pv);
        }
    }
    __syncthreads();

    // ---- GEMM 3: O[pix][c] = P[pix][t] @ Zw[t][c], accumulate into convres
    {
        const unsigned short* pa = p_bf + (mt0 * 16 + m) * 72 + quad * 8;
        const unsigned short* zc = g_Zwc + (nt0 * 16 + m) * 64 + quad * 8;
        f32x4 o = {0.f, 0.f, 0.f, 0.f};
        o = __builtin_amdgcn_mfma_f32_16x16x32_bf16(*(const bf16x8*)(pa),
                                                    *(const bf16x8*)(zc), o, 0, 0, 0);
        o = __builtin_amdgcn_mfma_f32_16x16x32_bf16(*(const bf16x8*)(pa + 32),
                                                    *(const bf16x8*)(zc + 32), o, 0, 0, 0);
#pragma unroll
        for (int r = 0; r < 4; ++r) {
            convres[(mt0 * 16 + quad * 4 + r) * 81 + nt0 * 16 + m] += o[r];
        }
    }
    __syncthreads();

    // ---- coalesced store: each wave stores 4 channels for all 64 pixels
    int ob = (b << 18) + (h << 6) + w;
#pragma unroll
    for (int kk = 0; kk < 4; ++kk) {
        int c = wid * 4 + kk;
        out[ob + (c << 12)] = convres[lane * 81 + c] + g_cb[c];
    }
}

// ---------------------------------------------------------------------------
extern "C" void kernel_launch(void* const* d_in, const int* in_sizes, int n_in,
                              void* d_out, int out_size, void* d_ws, size_t ws_size,
                              hipStream_t stream) {
    const float* x     = (const float*)d_in[0];
    const float* style = (const float*)d_in[1];
    const float* dw    = (const float*)d_in[2];
    const float* dpb   = (const float*)d_in[3];
    const float* s2dw  = (const float*)d_in[4];
    const float* s2db  = (const float*)d_in[5];
    const float* qcnn  = (const float*)d_in[6];
    const float* meas  = (const float*)d_in[7];
    const float* outw  = (const float*)d_in[8];
    const float* outb  = (const float*)d_in[9];
    const float* rw    = (const float*)d_in[10];
    const float* resb  = (const float*)d_in[11];
    float* out = (float*)d_out;

    hipLaunchKernelGGL(k_prep, dim3(156), dim3(64), 0, stream,
                       style, dw, rw, s2dw, s2db, qcnn, meas, outw, outb, resb);
    hipLaunchKernelGGL(k_main, dim3(512), dim3(1024), 0, stream, x, dpb, out);
}